// Round 4
// baseline (870.695 us; speedup 1.0000x reference)
//
#include <hip/hip_runtime.h>
#include <hip/hip_bf16.h>

typedef __attribute__((ext_vector_type(8))) short bf16x8;
typedef __attribute__((ext_vector_type(4))) float f32x4;

union U16 { int4 v; ushort u[8]; };

__device__ __forceinline__ float b2f(ushort u){ return __uint_as_float(((unsigned int)u)<<16); }
__device__ __forceinline__ ushort f2b(float f){ return __bfloat16_as_ushort(__float2bfloat16(f)); }
__device__ __forceinline__ f32x4 mfma16(bf16x8 a, bf16x8 b, f32x4 c){
  return __builtin_amdgcn_mfma_f32_16x16x32_bf16(a,b,c,0,0,0);
}

// ---------------- prep: weights -> bf16 ----------------
__global__ void k_prep(const float* __restrict__ Wfx, const float* __restrict__ bfx,
                       const float* __restrict__ Wx,  const float* __restrict__ bx,
                       const float* __restrict__ Wout, const float* __restrict__ Wsl,
                       ushort* __restrict__ Wcat, float* __restrict__ bcat,
                       ushort* __restrict__ Wo16, ushort* __restrict__ Wsl16){
  int i = blockIdx.x*256 + threadIdx.x;           // 0..262143
  if (i < 131072) Wcat[i] = f2b(Wfx[i]);
  else if (i < 262144) Wcat[i] = f2b(Wx[i-131072]);
  if (i < 131072) Wo16[i] = f2b(Wout[i]);
  if (i < 4096) Wsl16[i] = f2b(Wsl[i]);
  if (i < 512) bcat[i] = bfx[i];
  else if (i < 1024) bcat[i] = bx[i-512];
}

__global__ void k_zero(float* __restrict__ p, int n){
  int i = blockIdx.x*256 + threadIdx.x;
  if (i < n) p[i] = 0.f;
}

// ---------------- xcvt: x f32 -> bf16 ----------------
__global__ void k_xcvt(const float* __restrict__ x, ushort* __restrict__ xb){
  const size_t i = ((size_t)blockIdx.x*256 + threadIdx.x)*8;   // 16384 blocks exact
  float4 a = *(const float4*)&x[i];
  float4 b = *(const float4*)&x[i+4];
  U16 o;
  o.u[0]=f2b(a.x); o.u[1]=f2b(a.y); o.u[2]=f2b(a.z); o.u[3]=f2b(a.w);
  o.u[4]=f2b(b.x); o.u[5]=f2b(b.y); o.u[6]=f2b(b.z); o.u[7]=f2b(b.w);
  *(int4*)&xb[i] = o.v;
}

// ---------------- proj: [fx|xm] = x @ Wcat^T + bcat  (MFMA, 4-tile pipelined) ----------------
__global__ __launch_bounds__(256,3) void k_proj(
    const ushort* __restrict__ xb, const ushort* __restrict__ Wcat,
    const float* __restrict__ bcat, ushort* __restrict__ fx, ushort* __restrict__ xm){
  __shared__ ushort lA[64*264];                   // [64 tok][256+8 pad] bf16
  const int t = threadIdx.x;
  const int w=t>>6, l=t&63, l16=l&15, q8=l>>4;
  const int j0 = blockIdx.y*256 + w*64;
  const int srow = t>>5, scol = (t&31)*8;         // stage: rows i*8+srow, 16B chunks
  const long tokbase = (long)blockIdx.x*256;
  int4 stg[8];
  // prologue: tile 0 -> regs -> LDS
  for (int i=0;i<8;i++)
    stg[i] = *(const int4*)&xb[(size_t)(tokbase + i*8 + srow)*256 + scol];
  for (int i=0;i<8;i++)
    *(int4*)&lA[(i*8+srow)*264 + scol] = stg[i];
  __syncthreads();
  for (int tt=0; tt<4; tt++){
    const long tok0 = tokbase + tt*64;
    if (tt<3){                                    // issue next tile's loads early (T14)
      const long nt = tok0 + 64;
      for (int i=0;i<8;i++)
        stg[i] = *(const int4*)&xb[(size_t)(nt + i*8 + srow)*256 + scol];
    }
    f32x4 acc[4][4] = {};
    #pragma unroll 2
    for (int ks=0; ks<8; ks++){
      bf16x8 af[4], bfg[4];
      for (int i=0;i<4;i++) af[i] = *(const bf16x8*)&lA[(i*16+l16)*264 + ks*32 + q8*8];
      for (int j=0;j<4;j++) bfg[j] = *(const bf16x8*)&Wcat[(size_t)(j0+j*16+l16)*256 + ks*32 + q8*8];
      for (int i=0;i<4;i++)
        for (int j=0;j<4;j++)
          acc[i][j] = mfma16(af[i], bfg[j], acc[i][j]);
    }
    for (int j=0;j<4;j++){
      const int col = j0 + j*16 + l16;
      const float bc = bcat[col];
      ushort* dst = (col<512) ? fx : xm;
      const int cc = (col<512) ? col : col-512;
      for (int i=0;i<4;i++)
        for (int r=0;r<4;r++)
          dst[(size_t)(tok0 + i*16 + q8*4 + r)*512 + cc] = f2b(acc[i][j][r] + bc);
    }
    if (tt<3){
      __syncthreads();                            // all waves done reading lA
      for (int i=0;i<8;i++)
        *(int4*)&lA[(i*8+srow)*264 + scol] = stg[i];
      __syncthreads();
    }
  }
}

// ---------------- slice: softmax((xm@Wslice^T+b)/temp) -> swn + colsum  (MFMA) ----------------
__global__ __launch_bounds__(256,4) void k_slice(
    const ushort* __restrict__ xm, const ushort* __restrict__ Wsl16,
    const float* __restrict__ bslv, const float* __restrict__ temp,
    ushort* __restrict__ swn, float* __restrict__ cs){
  __shared__ float lcs[512];
  const int t = threadIdx.x, w=t>>6, l=t&63, l16=l&15, q8=l>>4;
  const long tok0 = (long)blockIdx.x*64;
  const int b = (int)(tok0 >> 15);
  for (int i=t;i<512;i+=256) lcs[i]=0.f;
  bf16x8 bw[4][2];
  for (int j=0;j<4;j++)
    for (int ks=0;ks<2;ks++)
      bw[j][ks] = *(const bf16x8*)&Wsl16[(j*16+l16)*64 + ks*32 + q8*8];
  float bj[4];
  for (int j=0;j<4;j++) bj[j] = bslv[j*16+l16];
  float itemp[8];
  for (int h=0;h<8;h++){
    float tp = temp[h]; tp = fminf(fmaxf(tp,0.1f),5.0f); itemp[h] = 1.0f/tp;
  }
  __syncthreads();
  const size_t rowbase = (size_t)(tok0 + w*16 + l16)*512;
  for (int h=0;h<8;h++){
    bf16x8 af0 = *(const bf16x8*)&xm[rowbase + h*64 + q8*8];
    bf16x8 af1 = *(const bf16x8*)&xm[rowbase + h*64 + 32 + q8*8];
    f32x4 acc[4] = {};
    for (int j=0;j<4;j++) acc[j] = mfma16(af0, bw[j][0], acc[j]);
    for (int j=0;j<4;j++) acc[j] = mfma16(af1, bw[j][1], acc[j]);
    const float it = itemp[h];
    float csum[4] = {0.f,0.f,0.f,0.f};
    for (int r=0;r<4;r++){
      float v[4]; float m = -1e30f;
      for (int j=0;j<4;j++){ v[j] = (acc[j][r] + bj[j])*it; m = fmaxf(m, v[j]); }
      for (int mk=1;mk<16;mk<<=1) m = fmaxf(m, __shfl_xor(m, mk, 64));
      float s = 0.f;
      for (int j=0;j<4;j++){ v[j] = __expf(v[j]-m); s += v[j]; }
      for (int mk=1;mk<16;mk<<=1) s += __shfl_xor(s, mk, 64);
      const float inv = 1.0f/s;
      const long tok = tok0 + w*16 + q8*4 + r;
      ushort* dst = &swn[((size_t)tok*8 + h)*64];
      for (int j=0;j<4;j++){
        float q = b2f(f2b(v[j]*inv));   // bf16-round FIRST: cs == sum of consumed weights
        csum[j] += q;
        dst[j*16+l16] = f2b(q);
      }
    }
    for (int j=0;j<4;j++){
      float v = csum[j];
      v += __shfl_xor(v, 16, 64);
      v += __shfl_xor(v, 32, 64);
      if (q8==0) atomicAdd(&lcs[h*64 + j*16 + l16], v);
    }
  }
  __syncthreads();
  for (int i=t;i<512;i+=256) atomicAdd(&cs[(size_t)b*512 + i], lcs[i]);
}

// ---------------- accum: slice_raw[bh][g][c] += sum_n sw[n][g]*fx[n][c]  (MFMA) ----------------
__global__ __launch_bounds__(256,2) void k_accum(
    const ushort* __restrict__ swn, const ushort* __restrict__ fx,
    float* __restrict__ sraw){
  __shared__ ushort lW[64*136];   // sw^T [g][128n + pad]
  __shared__ ushort lF[64*136];   // fx^T [c][128n + pad]
  const int t = threadIdx.x;
  const int bh = blockIdx.y, b = bh>>3, h = bh&7;
  const long tokb = (long)b*32768 + (long)blockIdx.x*1024;
  const int w=t>>6, l=t&63, l16=l&15, q8=l>>4;
  const int nr = t>>3, g8 = (t&7)*8;
  f32x4 acc[4] = {};
  for (int sub=0; sub<8; sub++){
    __syncthreads();
    for (int ri=0; ri<4; ri++){
      const int nl = ri*32 + nr;
      const long tok = tokb + sub*128 + nl;
      U16 sv; sv.v = *(const int4*)&swn[((size_t)tok*8 + h)*64 + g8];
      U16 fv; fv.v = *(const int4*)&fx[(size_t)tok*512 + h*64 + g8];
      for (int j=0;j<8;j++){
        lW[(g8+j)*136 + nl] = sv.u[j];
        lF[(g8+j)*136 + nl] = fv.u[j];
      }
    }
    __syncthreads();
    #pragma unroll
    for (int kk=0; kk<4; kk++){
      bf16x8 af = *(const bf16x8*)&lW[(w*16+l16)*136 + kk*32 + q8*8];
      for (int j=0;j<4;j++){
        bf16x8 bfg = *(const bf16x8*)&lF[(j*16+l16)*136 + kk*32 + q8*8];
        acc[j] = mfma16(af, bfg, acc[j]);
      }
    }
  }
  for (int j=0;j<4;j++)
    for (int r=0;r<4;r++)
      atomicAdd(&sraw[((size_t)bh*64 + w*16 + q8*4 + r)*64 + j*16 + l16], acc[j][r]);
}

// ---------------- tiny slice attention per (b,h) ----------------
__global__ __launch_bounds__(256,1) void k_attn(
    const float* __restrict__ sraw, const float* __restrict__ cs,
    const float* __restrict__ Wq, const float* __restrict__ Wk, const float* __restrict__ Wv,
    ushort* __restrict__ ott){
  __shared__ float st[64*68], t1[64*68], t2[64*68];
  __shared__ ushort tw[64*68];
  __shared__ float pmax[256], psum[256], csl[64];
  const int t = threadIdx.x, bh = blockIdx.x;
  if (t < 64) csl[t] = 1.0f/(cs[bh*64+t] + 1e-5f);
  __syncthreads();
  for (int i=0;i<16;i++){ int idx=i*256+t; st[(idx>>6)*68+(idx&63)] = sraw[(size_t)bh*4096+idx]*csl[idx>>6]; }
  for (int i=0;i<16;i++){ int idx=i*256+t; tw[(idx>>6)*68+(idx&63)] = f2b(Wq[idx]); }
  __syncthreads();
  const int w=t>>6, lane=t&63;
  float o[16];
  #define GT(OUT) do{ for(int j=0;j<16;j++) OUT[j]=0.f; \
    for(int c4=0;c4<16;c4++){ float4 xv=*(float4*)&st[lane*68+c4*4]; \
      for(int j=0;j<16;j++){ ushort4 wv=*(const ushort4*)&tw[(w*16+j)*68+c4*4]; \
        OUT[j]+=xv.x*b2f(wv.x)+xv.y*b2f(wv.y)+xv.z*b2f(wv.z)+xv.w*b2f(wv.w);} } }while(0)
  GT(o);                                   // q
  __syncthreads();
  for (int j=0;j<16;j++) t1[lane*68 + w*16+j] = o[j];
  for (int i=0;i<16;i++){ int idx=i*256+t; tw[(idx>>6)*68+(idx&63)] = f2b(Wk[idx]); }
  __syncthreads();
  GT(o);                                   // k
  __syncthreads();
  for (int j=0;j<16;j++) t2[lane*68 + w*16+j] = o[j];
  __syncthreads();
  float sc[16];
  for (int j=0;j<16;j++) sc[j]=0.f;
  for (int c4=0;c4<16;c4++){
    float4 qv = *(float4*)&t1[lane*68+c4*4];
    for (int j=0;j<16;j++){
      float4 kv = *(float4*)&t2[(w*16+j)*68+c4*4];
      sc[j] += qv.x*kv.x + qv.y*kv.y + qv.z*kv.z + qv.w*kv.w;
    }
  }
  float pm = -1e30f;
  for (int j=0;j<16;j++){ sc[j]*=0.125f; pm=fmaxf(pm,sc[j]); }
  pmax[lane*4+w]=pm; __syncthreads();
  const float m = fmaxf(fmaxf(pmax[lane*4+0],pmax[lane*4+1]),fmaxf(pmax[lane*4+2],pmax[lane*4+3]));
  float s=0.f;
  for (int j=0;j<16;j++){ sc[j]=__expf(sc[j]-m); s+=sc[j]; }
  psum[lane*4+w]=s; __syncthreads();
  const float inv = 1.0f/(psum[lane*4+0]+psum[lane*4+1]+psum[lane*4+2]+psum[lane*4+3]);
  for (int j=0;j<16;j++) t1[lane*68 + w*16+j] = sc[j]*inv;     // attn (q dead)
  for (int i=0;i<16;i++){ int idx=i*256+t; tw[(idx>>6)*68+(idx&63)] = f2b(Wv[idx]); }
  __syncthreads();
  GT(o);                                   // v
  __syncthreads();
  for (int j=0;j<16;j++) t2[lane*68 + w*16+j] = o[j];          // v (k dead)
  __syncthreads();
  float ot[16];
  for (int j=0;j<16;j++) ot[j]=0.f;
  for (int m4=0;m4<16;m4++){
    float4 av = *(float4*)&t1[lane*68+m4*4];
    for (int j=0;j<16;j++){
      int c = w*16+j;
      ot[j] += av.x*t2[(m4*4+0)*68+c] + av.y*t2[(m4*4+1)*68+c]
             + av.z*t2[(m4*4+2)*68+c] + av.w*t2[(m4*4+3)*68+c];
    }
  }
  const float ics = csl[lane];
  for (int j=0;j<16;j++)
    ott[(size_t)bh*4096 + (size_t)(w*16+j)*64 + lane] = f2b(ot[j]*ics);
  #undef GT
}

// ---------------- deslice: out_x[n][h*64+c] = sum_g sw[n][g]*ot'[g][c]  (MFMA) ----------------
__global__ __launch_bounds__(256,2) void k_deslice(
    const ushort* __restrict__ swn, const ushort* __restrict__ ott,
    ushort* __restrict__ ox){
  __shared__ ushort lS[32*520];
  const int t = threadIdx.x;
  const long tok0 = (long)blockIdx.x*32;
  const int b = (int)(tok0 >> 15);
  const int rw = t>>3, sg = t&7;
  for (int i=0;i<8;i++)
    *(int4*)&lS[rw*520 + i*64 + sg*8] = *(const int4*)&swn[(size_t)(tok0+rw)*512 + i*64 + sg*8];
  __syncthreads();
  const int w=t>>6, l=t&63, l16=l&15, q8=l>>4;
  for (int h=0; h<8; h++){
    const int bh = b*8 + h;
    f32x4 acc[2] = {};
    for (int kb=0; kb<2; kb++){
      bf16x8 bfg = *(const bf16x8*)&ott[(size_t)(bh*64 + w*16 + l16)*64 + kb*32 + q8*8];
      for (int i=0;i<2;i++){
        bf16x8 af = *(const bf16x8*)&lS[(i*16+l16)*520 + h*64 + kb*32 + q8*8];
        acc[i] = mfma16(af, bfg, acc[i]);
      }
    }
    for (int i=0;i<2;i++)
      for (int r=0;r<4;r++)
        ox[(size_t)(tok0 + i*16 + q8*4 + r)*512 + h*64 + w*16 + l16] = f2b(acc[i][r]);
  }
}

// ---------------- out: out = out_x @ Wout^T + bout  (MFMA, f32 out) ----------------
__global__ __launch_bounds__(256,2) void k_out(
    const ushort* __restrict__ ox, const ushort* __restrict__ Wo16,
    const float* __restrict__ bout, float* __restrict__ out){
  __shared__ ushort lA[32*520];
  const int t = threadIdx.x;
  const long tok0 = (long)blockIdx.x*32;
  const int rw = t>>3, sg = t&7;
  for (int i=0;i<8;i++)
    *(int4*)&lA[rw*520 + i*64 + sg*8] = *(const int4*)&ox[(size_t)(tok0+rw)*512 + i*64 + sg*8];
  __syncthreads();
  const int w=t>>6, l=t&63, l16=l&15, q8=l>>4;
  const int j0 = w*64;
  f32x4 acc[2][4] = {};
  #pragma unroll 2
  for (int ks=0; ks<16; ks++){
    bf16x8 af[2], bfg[4];
    for (int i=0;i<2;i++) af[i] = *(const bf16x8*)&lA[(i*16+l16)*520 + ks*32 + q8*8];
    for (int j=0;j<4;j++) bfg[j] = *(const bf16x8*)&Wo16[(size_t)(j0+j*16+l16)*512 + ks*32 + q8*8];
    for (int i=0;i<2;i++)
      for (int j=0;j<4;j++)
        acc[i][j] = mfma16(af[i], bfg[j], acc[i][j]);
  }
  for (int j=0;j<4;j++){
    const int col = j0 + j*16 + l16;
    const float bc = bout[col];
    for (int i=0;i<2;i++)
      for (int r=0;r<4;r++)
        out[(size_t)(tok0 + i*16 + q8*4 + r)*256 + col] = acc[i][j][r] + bc;
  }
}

extern "C" void kernel_launch(void* const* d_in, const int* in_sizes, int n_in,
                              void* d_out, int out_size, void* d_ws, size_t ws_size,
                              hipStream_t stream) {
  (void)in_sizes; (void)n_in; (void)out_size;
  const float* x    = (const float*)d_in[0];
  const float* Wfx  = (const float*)d_in[1];
  const float* bfx  = (const float*)d_in[2];
  const float* Wx   = (const float*)d_in[3];
  const float* bx   = (const float*)d_in[4];
  const float* Wsl  = (const float*)d_in[5];
  const float* bsl  = (const float*)d_in[6];
  const float* temp = (const float*)d_in[7];
  const float* Wq   = (const float*)d_in[8];
  const float* Wk   = (const float*)d_in[9];
  const float* Wv   = (const float*)d_in[10];
  const float* Wout = (const float*)d_in[11];
  const float* bout = (const float*)d_in[12];
  float* out = (float*)d_out;
  char* ws = (char*)d_ws;

  constexpr size_t O_FX   = 0;                       // ushort [131072][512]
  constexpr size_t O_XM   = 134217728;               // ushort [131072][512] (reused as out_x)
  constexpr size_t O_SWN  = 268435456;               // ushort [131072][8][64]; first 67MB = xb during proj
  constexpr size_t O_SRAW = 402653184;               // float  [32][64][64]
  constexpr size_t O_CS   = O_SRAW + 524288;         // float  [32][64]
  constexpr size_t O_OTT  = O_CS + 8192;             // ushort [32][64][64]
  constexpr size_t O_WCAT = O_OTT + 262144;          // ushort [1024][256]
  constexpr size_t O_BCAT = O_WCAT + 524288;         // float  [1024]
  constexpr size_t O_WOUT = O_BCAT + 4096;           // ushort [256][512]
  constexpr size_t O_WSL  = O_WOUT + 262144;         // ushort [64][64]
  constexpr size_t NEED   = O_WSL + 8192;            // ~386 MiB
  if (ws_size < NEED) return;

  ushort* fxb  = (ushort*)(ws + O_FX);
  ushort* xmb  = (ushort*)(ws + O_XM);
  ushort* swn  = (ushort*)(ws + O_SWN);
  ushort* xb   = (ushort*)(ws + O_SWN);   // aliases swn: xb dead before k_slice writes swn
  float*  sraw = (float*)(ws + O_SRAW);
  float*  cs   = (float*)(ws + O_CS);
  ushort* ott  = (ushort*)(ws + O_OTT);
  ushort* Wcat = (ushort*)(ws + O_WCAT);
  float*  bcat = (float*)(ws + O_BCAT);
  ushort* Wo16 = (ushort*)(ws + O_WOUT);
  ushort* Wsl16= (ushort*)(ws + O_WSL);
  ushort* oxb  = xmb;   // out_x aliases xm (dead after k_slice)

  k_prep<<<1024,256,0,stream>>>(Wfx,bfx,Wx,bx,Wout,Wsl,Wcat,bcat,Wo16,Wsl16);
  k_zero<<<520,256,0,stream>>>(sraw, 133120);        // sraw + cs contiguous
  k_xcvt<<<16384,256,0,stream>>>(x,xb);
  k_proj<<<dim3(512,4),256,0,stream>>>(xb,Wcat,bcat,fxb,xmb);
  k_slice<<<2048,256,0,stream>>>(xmb,Wsl16,bsl,temp,swn,cs);
  k_accum<<<dim3(32,32),256,0,stream>>>(swn,fxb,sraw);
  k_attn<<<32,256,0,stream>>>(sraw,cs,Wq,Wk,Wv,ott);
  k_deslice<<<4096,256,0,stream>>>(swn,ott,oxb);
  k_out<<<4096,256,0,stream>>>(oxb,Wo16,bout,out);
}

// Round 5
// 708.663 us; speedup vs baseline: 1.2286x; 1.2286x over previous
//
#include <hip/hip_runtime.h>
#include <hip/hip_bf16.h>

typedef __attribute__((ext_vector_type(8))) short bf16x8;
typedef __attribute__((ext_vector_type(4))) float f32x4;

union U16 { int4 v; ushort u[8]; };

__device__ __forceinline__ float b2f(ushort u){ return __uint_as_float(((unsigned int)u)<<16); }
__device__ __forceinline__ ushort f2b(float f){ return __bfloat16_as_ushort(__float2bfloat16(f)); }
__device__ __forceinline__ f32x4 mfma16(bf16x8 a, bf16x8 b, f32x4 c){
  return __builtin_amdgcn_mfma_f32_16x16x32_bf16(a,b,c,0,0,0);
}

// ---------------- prep: weights -> bf16 ----------------
__global__ void k_prep(const float* __restrict__ Wfx, const float* __restrict__ bfx,
                       const float* __restrict__ Wx,  const float* __restrict__ bx,
                       const float* __restrict__ Wout, const float* __restrict__ Wsl,
                       ushort* __restrict__ Wcat, float* __restrict__ bcat,
                       ushort* __restrict__ Wo16, ushort* __restrict__ Wsl16){
  int i = blockIdx.x*256 + threadIdx.x;           // 0..262143
  if (i < 131072) Wcat[i] = f2b(Wfx[i]);
  else if (i < 262144) Wcat[i] = f2b(Wx[i-131072]);
  if (i < 131072) Wo16[i] = f2b(Wout[i]);
  if (i < 4096) Wsl16[i] = f2b(Wsl[i]);
  if (i < 512) bcat[i] = bfx[i];
  else if (i < 1024) bcat[i] = bx[i-512];
}

__global__ void k_zero(float* __restrict__ p, int n){
  int i = blockIdx.x*256 + threadIdx.x;
  if (i < n) p[i] = 0.f;
}

// ---------------- xcvt: x f32 -> bf16 ----------------
__global__ void k_xcvt(const float* __restrict__ x, ushort* __restrict__ xb){
  const size_t i = ((size_t)blockIdx.x*256 + threadIdx.x)*8;   // 16384 blocks exact
  float4 a = *(const float4*)&x[i];
  float4 b = *(const float4*)&x[i+4];
  U16 o;
  o.u[0]=f2b(a.x); o.u[1]=f2b(a.y); o.u[2]=f2b(a.z); o.u[3]=f2b(a.w);
  o.u[4]=f2b(b.x); o.u[5]=f2b(b.y); o.u[6]=f2b(b.z); o.u[7]=f2b(b.w);
  *(int4*)&xb[i] = o.v;
}

// ---------------- proj: [fx|xm] = x @ Wcat^T + bcat  (128x128 dbuf MFMA GEMM) ----------------
__global__ __launch_bounds__(256,3) void k_proj(
    const ushort* __restrict__ xb, const ushort* __restrict__ Wcat,
    const float* __restrict__ bcat, ushort* __restrict__ fx, ushort* __restrict__ xm){
  __shared__ ushort lA[2][128*40];
  __shared__ ushort lB[2][128*40];
  const int t = threadIdx.x;
  const int w=t>>6, l=t&63, l16=l&15, q8=l>>4;
  const int wm = w>>1, wn = w&1;
  const long m0 = (long)blockIdx.x*128;
  const int n0 = blockIdx.y*128;
  const int srow = t>>2, sseg = (t&3)*8;
  int4 a0,a1,b0,b1;
  a0 = *(const int4*)&xb[(size_t)(m0+srow)*256 + sseg];
  a1 = *(const int4*)&xb[(size_t)(m0+64+srow)*256 + sseg];
  b0 = *(const int4*)&Wcat[(size_t)(n0+srow)*256 + sseg];
  b1 = *(const int4*)&Wcat[(size_t)(n0+64+srow)*256 + sseg];
  *(int4*)&lA[0][srow*40+sseg] = a0; *(int4*)&lA[0][(64+srow)*40+sseg] = a1;
  *(int4*)&lB[0][srow*40+sseg] = b0; *(int4*)&lB[0][(64+srow)*40+sseg] = b1;
  __syncthreads();
  f32x4 acc[4][4] = {};
  for (int ks=0; ks<8; ks++){
    const int cur = ks&1, nxt = cur^1;
    if (ks<7){
      const int ko = (ks+1)*32;
      a0 = *(const int4*)&xb[(size_t)(m0+srow)*256 + ko + sseg];
      a1 = *(const int4*)&xb[(size_t)(m0+64+srow)*256 + ko + sseg];
      b0 = *(const int4*)&Wcat[(size_t)(n0+srow)*256 + ko + sseg];
      b1 = *(const int4*)&Wcat[(size_t)(n0+64+srow)*256 + ko + sseg];
    }
    bf16x8 af[4], bfg[4];
    for (int i=0;i<4;i++) af[i]  = *(const bf16x8*)&lA[cur][(wm*64+i*16+l16)*40 + q8*8];
    for (int j=0;j<4;j++) bfg[j] = *(const bf16x8*)&lB[cur][(wn*64+j*16+l16)*40 + q8*8];
    for (int i=0;i<4;i++)
      for (int j=0;j<4;j++)
        acc[i][j] = mfma16(af[i], bfg[j], acc[i][j]);
    if (ks<7){
      *(int4*)&lA[nxt][srow*40+sseg] = a0; *(int4*)&lA[nxt][(64+srow)*40+sseg] = a1;
      *(int4*)&lB[nxt][srow*40+sseg] = b0; *(int4*)&lB[nxt][(64+srow)*40+sseg] = b1;
    }
    __syncthreads();
  }
  ushort* dst = (n0 < 512) ? fx : xm;
  const int nb = (n0 < 512) ? n0 : n0-512;
  for (int j=0;j<4;j++){
    const int colg = n0 + wn*64 + j*16 + l16;
    const float bc = bcat[colg];
    const int col = nb + wn*64 + j*16 + l16;
    for (int i=0;i<4;i++)
      for (int r=0;r<4;r++)
        dst[(size_t)(m0 + wm*64 + i*16 + q8*4 + r)*512 + col] = f2b(acc[i][j][r] + bc);
  }
}

// ---------------- slice: softmax((xm@Wslice^T+b)/temp) -> swn + colsum  (MFMA) ----------------
__global__ __launch_bounds__(256,4) void k_slice(
    const ushort* __restrict__ xm, const ushort* __restrict__ Wsl16,
    const float* __restrict__ bslv, const float* __restrict__ temp,
    ushort* __restrict__ swn, float* __restrict__ cs){
  __shared__ float lcs[512];
  const int t = threadIdx.x, w=t>>6, l=t&63, l16=l&15, q8=l>>4;
  const long tok0 = (long)blockIdx.x*64;
  const int b = (int)(tok0 >> 15);
  for (int i=t;i<512;i+=256) lcs[i]=0.f;
  bf16x8 bw[4][2];
  for (int j=0;j<4;j++)
    for (int ks=0;ks<2;ks++)
      bw[j][ks] = *(const bf16x8*)&Wsl16[(j*16+l16)*64 + ks*32 + q8*8];
  float bj[4];
  for (int j=0;j<4;j++) bj[j] = bslv[j*16+l16];
  float itemp[8];
  for (int h=0;h<8;h++){
    float tp = temp[h]; tp = fminf(fmaxf(tp,0.1f),5.0f); itemp[h] = 1.0f/tp;
  }
  __syncthreads();
  const size_t rowbase = (size_t)(tok0 + w*16 + l16)*512;
  for (int h=0;h<8;h++){
    bf16x8 af0 = *(const bf16x8*)&xm[rowbase + h*64 + q8*8];
    bf16x8 af1 = *(const bf16x8*)&xm[rowbase + h*64 + 32 + q8*8];
    f32x4 acc[4] = {};
    for (int j=0;j<4;j++) acc[j] = mfma16(af0, bw[j][0], acc[j]);
    for (int j=0;j<4;j++) acc[j] = mfma16(af1, bw[j][1], acc[j]);
    const float it = itemp[h];
    float csum[4] = {0.f,0.f,0.f,0.f};
    for (int r=0;r<4;r++){
      float v[4]; float m = -1e30f;
      for (int j=0;j<4;j++){ v[j] = (acc[j][r] + bj[j])*it; m = fmaxf(m, v[j]); }
      for (int mk=1;mk<16;mk<<=1) m = fmaxf(m, __shfl_xor(m, mk, 64));
      float s = 0.f;
      for (int j=0;j<4;j++){ v[j] = __expf(v[j]-m); s += v[j]; }
      for (int mk=1;mk<16;mk<<=1) s += __shfl_xor(s, mk, 64);
      const float inv = 1.0f/s;
      const long tok = tok0 + w*16 + q8*4 + r;
      ushort* dst = &swn[((size_t)tok*8 + h)*64];
      for (int j=0;j<4;j++){
        float q = b2f(f2b(v[j]*inv));   // bf16-round FIRST: cs == sum of consumed weights
        csum[j] += q;
        dst[j*16+l16] = f2b(q);
      }
    }
    for (int j=0;j<4;j++){
      float v = csum[j];
      v += __shfl_xor(v, 16, 64);
      v += __shfl_xor(v, 32, 64);
      if (q8==0) atomicAdd(&lcs[h*64 + j*16 + l16], v);
    }
  }
  __syncthreads();
  for (int i=t;i<512;i+=256) atomicAdd(&cs[(size_t)b*512 + i], lcs[i]);
}

// ---------------- accum: slice_raw[bh][g][c] += sum_n sw[n][g]*fx[n][c]  (MFMA) ----------------
__global__ __launch_bounds__(256,2) void k_accum(
    const ushort* __restrict__ swn, const ushort* __restrict__ fx,
    float* __restrict__ sraw){
  __shared__ ushort lW[64*136];   // sw^T [g][128n + pad]
  __shared__ ushort lF[64*136];   // fx^T [c][128n + pad]
  const int t = threadIdx.x;
  const int bh = blockIdx.y, b = bh>>3, h = bh&7;
  const long tokb = (long)b*32768 + (long)blockIdx.x*1024;
  const int w=t>>6, l=t&63, l16=l&15, q8=l>>4;
  const int nr = t>>3, g8 = (t&7)*8;
  f32x4 acc[4] = {};
  for (int sub=0; sub<8; sub++){
    __syncthreads();
    for (int ri=0; ri<4; ri++){
      const int nl = ri*32 + nr;
      const long tok = tokb + sub*128 + nl;
      U16 sv; sv.v = *(const int4*)&swn[((size_t)tok*8 + h)*64 + g8];
      U16 fv; fv.v = *(const int4*)&fx[(size_t)tok*512 + h*64 + g8];
      for (int j=0;j<8;j++){
        lW[(g8+j)*136 + nl] = sv.u[j];
        lF[(g8+j)*136 + nl] = fv.u[j];
      }
    }
    __syncthreads();
    #pragma unroll
    for (int kk=0; kk<4; kk++){
      bf16x8 af = *(const bf16x8*)&lW[(w*16+l16)*136 + kk*32 + q8*8];
      for (int j=0;j<4;j++){
        bf16x8 bfg = *(const bf16x8*)&lF[(j*16+l16)*136 + kk*32 + q8*8];
        acc[j] = mfma16(af, bfg, acc[j]);
      }
    }
  }
  for (int j=0;j<4;j++)
    for (int r=0;r<4;r++)
      atomicAdd(&sraw[((size_t)bh*64 + w*16 + q8*4 + r)*64 + j*16 + l16], acc[j][r]);
}

// ---------------- tiny slice attention per (b,h) ----------------
__global__ __launch_bounds__(256,1) void k_attn(
    const float* __restrict__ sraw, const float* __restrict__ cs,
    const float* __restrict__ Wq, const float* __restrict__ Wk, const float* __restrict__ Wv,
    ushort* __restrict__ ott){
  __shared__ float st[64*68], t1[64*68], t2[64*68];
  __shared__ ushort tw[64*68];
  __shared__ float pmax[256], psum[256], csl[64];
  const int t = threadIdx.x, bh = blockIdx.x;
  if (t < 64) csl[t] = 1.0f/(cs[bh*64+t] + 1e-5f);
  __syncthreads();
  for (int i=0;i<16;i++){ int idx=i*256+t; st[(idx>>6)*68+(idx&63)] = sraw[(size_t)bh*4096+idx]*csl[idx>>6]; }
  for (int i=0;i<16;i++){ int idx=i*256+t; tw[(idx>>6)*68+(idx&63)] = f2b(Wq[idx]); }
  __syncthreads();
  const int w=t>>6, lane=t&63;
  float o[16];
  #define GT(OUT) do{ for(int j=0;j<16;j++) OUT[j]=0.f; \
    for(int c4=0;c4<16;c4++){ float4 xv=*(float4*)&st[lane*68+c4*4]; \
      for(int j=0;j<16;j++){ ushort4 wv=*(const ushort4*)&tw[(w*16+j)*68+c4*4]; \
        OUT[j]+=xv.x*b2f(wv.x)+xv.y*b2f(wv.y)+xv.z*b2f(wv.z)+xv.w*b2f(wv.w);} } }while(0)
  GT(o);                                   // q
  __syncthreads();
  for (int j=0;j<16;j++) t1[lane*68 + w*16+j] = o[j];
  for (int i=0;i<16;i++){ int idx=i*256+t; tw[(idx>>6)*68+(idx&63)] = f2b(Wk[idx]); }
  __syncthreads();
  GT(o);                                   // k
  __syncthreads();
  for (int j=0;j<16;j++) t2[lane*68 + w*16+j] = o[j];
  __syncthreads();
  float sc[16];
  for (int j=0;j<16;j++) sc[j]=0.f;
  for (int c4=0;c4<16;c4++){
    float4 qv = *(float4*)&t1[lane*68+c4*4];
    for (int j=0;j<16;j++){
      float4 kv = *(float4*)&t2[(w*16+j)*68+c4*4];
      sc[j] += qv.x*kv.x + qv.y*kv.y + qv.z*kv.z + qv.w*kv.w;
    }
  }
  float pm = -1e30f;
  for (int j=0;j<16;j++){ sc[j]*=0.125f; pm=fmaxf(pm,sc[j]); }
  pmax[lane*4+w]=pm; __syncthreads();
  const float m = fmaxf(fmaxf(pmax[lane*4+0],pmax[lane*4+1]),fmaxf(pmax[lane*4+2],pmax[lane*4+3]));
  float s=0.f;
  for (int j=0;j<16;j++){ sc[j]=__expf(sc[j]-m); s+=sc[j]; }
  psum[lane*4+w]=s; __syncthreads();
  const float inv = 1.0f/(psum[lane*4+0]+psum[lane*4+1]+psum[lane*4+2]+psum[lane*4+3]);
  for (int j=0;j<16;j++) t1[lane*68 + w*16+j] = sc[j]*inv;     // attn (q dead)
  for (int i=0;i<16;i++){ int idx=i*256+t; tw[(idx>>6)*68+(idx&63)] = f2b(Wv[idx]); }
  __syncthreads();
  GT(o);                                   // v
  __syncthreads();
  for (int j=0;j<16;j++) t2[lane*68 + w*16+j] = o[j];          // v (k dead)
  __syncthreads();
  float ot[16];
  for (int j=0;j<16;j++) ot[j]=0.f;
  for (int m4=0;m4<16;m4++){
    float4 av = *(float4*)&t1[lane*68+m4*4];
    for (int j=0;j<16;j++){
      int c = w*16+j;
      ot[j] += av.x*t2[(m4*4+0)*68+c] + av.y*t2[(m4*4+1)*68+c]
             + av.z*t2[(m4*4+2)*68+c] + av.w*t2[(m4*4+3)*68+c];
    }
  }
  const float ics = csl[lane];
  for (int j=0;j<16;j++)
    ott[(size_t)bh*4096 + (size_t)(w*16+j)*64 + lane] = f2b(ot[j]*ics);
  #undef GT
}

// ---------------- deslice: out_x[n][h*64+c] = sum_g sw[n][g]*ot'[g][c]  (MFMA) ----------------
__global__ __launch_bounds__(256,2) void k_deslice(
    const ushort* __restrict__ swn, const ushort* __restrict__ ott,
    ushort* __restrict__ ox){
  __shared__ ushort lS[32*520];
  const int t = threadIdx.x;
  const long tok0 = (long)blockIdx.x*32;
  const int b = (int)(tok0 >> 15);
  const int w=t>>6, l=t&63, l16=l&15, q8=l>>4;
  // preload all heads' B fragments into regs (kills per-h global latency)
  bf16x8 bo[8][2];
  for (int h=0;h<8;h++)
    for (int kb=0;kb<2;kb++)
      bo[h][kb] = *(const bf16x8*)&ott[(size_t)((b*8+h)*64 + w*16 + l16)*64 + kb*32 + q8*8];
  const int rw = t>>3, sg = t&7;
  for (int i=0;i<8;i++)
    *(int4*)&lS[rw*520 + i*64 + sg*8] = *(const int4*)&swn[(size_t)(tok0+rw)*512 + i*64 + sg*8];
  __syncthreads();
  for (int h=0; h<8; h++){
    f32x4 acc[2] = {};
    for (int kb=0; kb<2; kb++){
      for (int i=0;i<2;i++){
        bf16x8 af = *(const bf16x8*)&lS[(i*16+l16)*520 + h*64 + kb*32 + q8*8];
        acc[i] = mfma16(af, bo[h][kb], acc[i]);
      }
    }
    for (int i=0;i<2;i++)
      for (int r=0;r<4;r++)
        ox[(size_t)(tok0 + i*16 + q8*4 + r)*512 + h*64 + w*16 + l16] = f2b(acc[i][r]);
  }
}

// ---------------- out: out = out_x @ Wout^T + bout  (128x128 dbuf MFMA GEMM, f32 out) ----------------
__global__ __launch_bounds__(256,3) void k_out(
    const ushort* __restrict__ ox, const ushort* __restrict__ Wo16,
    const float* __restrict__ bout, float* __restrict__ out){
  __shared__ ushort lA[2][128*40];
  __shared__ ushort lB[2][128*40];
  const int t = threadIdx.x;
  const int w=t>>6, l=t&63, l16=l&15, q8=l>>4;
  const int wm = w>>1, wn = w&1;
  const long m0 = (long)blockIdx.x*128;
  const int n0 = blockIdx.y*128;
  const int srow = t>>2, sseg = (t&3)*8;
  int4 a0,a1,b0,b1;
  a0 = *(const int4*)&ox[(size_t)(m0+srow)*512 + sseg];
  a1 = *(const int4*)&ox[(size_t)(m0+64+srow)*512 + sseg];
  b0 = *(const int4*)&Wo16[(size_t)(n0+srow)*512 + sseg];
  b1 = *(const int4*)&Wo16[(size_t)(n0+64+srow)*512 + sseg];
  *(int4*)&lA[0][srow*40+sseg] = a0; *(int4*)&lA[0][(64+srow)*40+sseg] = a1;
  *(int4*)&lB[0][srow*40+sseg] = b0; *(int4*)&lB[0][(64+srow)*40+sseg] = b1;
  __syncthreads();
  f32x4 acc[2][4] = {};   // wave covers 32 tokens? no: 64x64 quadrant -> acc[4][4]
  f32x4 acc2[2][4] = {};  // split to keep names; treat acc(i) i=0..3 via two arrays
  for (int ks=0; ks<16; ks++){
    const int cur = ks&1, nxt = cur^1;
    if (ks<15){
      const int ko = (ks+1)*32;
      a0 = *(const int4*)&ox[(size_t)(m0+srow)*512 + ko + sseg];
      a1 = *(const int4*)&ox[(size_t)(m0+64+srow)*512 + ko + sseg];
      b0 = *(const int4*)&Wo16[(size_t)(n0+srow)*512 + ko + sseg];
      b1 = *(const int4*)&Wo16[(size_t)(n0+64+srow)*512 + ko + sseg];
    }
    bf16x8 af[4], bfg[4];
    for (int i=0;i<4;i++) af[i]  = *(const bf16x8*)&lA[cur][(wm*64+i*16+l16)*40 + q8*8];
    for (int j=0;j<4;j++) bfg[j] = *(const bf16x8*)&lB[cur][(wn*64+j*16+l16)*40 + q8*8];
    for (int j=0;j<4;j++){
      acc[0][j]  = mfma16(af[0], bfg[j], acc[0][j]);
      acc[1][j]  = mfma16(af[1], bfg[j], acc[1][j]);
      acc2[0][j] = mfma16(af[2], bfg[j], acc2[0][j]);
      acc2[1][j] = mfma16(af[3], bfg[j], acc2[1][j]);
    }
    if (ks<15){
      *(int4*)&lA[nxt][srow*40+sseg] = a0; *(int4*)&lA[nxt][(64+srow)*40+sseg] = a1;
      *(int4*)&lB[nxt][srow*40+sseg] = b0; *(int4*)&lB[nxt][(64+srow)*40+sseg] = b1;
    }
    __syncthreads();
  }
  for (int j=0;j<4;j++){
    const int col = n0 + wn*64 + j*16 + l16;
    const float bc = bout[col];
    for (int i=0;i<2;i++)
      for (int r=0;r<4;r++){
        out[(size_t)(m0 + wm*64 + i*16 + q8*4 + r)*256 + col] = acc[i][j][r] + bc;
        out[(size_t)(m0 + wm*64 + (i+2)*16 + q8*4 + r)*256 + col] = acc2[i][j][r] + bc;
      }
  }
}

extern "C" void kernel_launch(void* const* d_in, const int* in_sizes, int n_in,
                              void* d_out, int out_size, void* d_ws, size_t ws_size,
                              hipStream_t stream) {
  (void)in_sizes; (void)n_in; (void)out_size;
  const float* x    = (const float*)d_in[0];
  const float* Wfx  = (const float*)d_in[1];
  const float* bfx  = (const float*)d_in[2];
  const float* Wx   = (const float*)d_in[3];
  const float* bx   = (const float*)d_in[4];
  const float* Wsl  = (const float*)d_in[5];
  const float* bsl  = (const float*)d_in[6];
  const float* temp = (const float*)d_in[7];
  const float* Wq   = (const float*)d_in[8];
  const float* Wk   = (const float*)d_in[9];
  const float* Wv   = (const float*)d_in[10];
  const float* Wout = (const float*)d_in[11];
  const float* bout = (const float*)d_in[12];
  float* out = (float*)d_out;
  char* ws = (char*)d_ws;

  constexpr size_t O_FX   = 0;                       // ushort [131072][512]
  constexpr size_t O_XM   = 134217728;               // ushort [131072][512] (reused as out_x)
  constexpr size_t O_SWN  = 268435456;               // ushort [131072][8][64]; first 67MB = xb during proj
  constexpr size_t O_SRAW = 402653184;               // float  [32][64][64]
  constexpr size_t O_CS   = O_SRAW + 524288;         // float  [32][64]
  constexpr size_t O_OTT  = O_CS + 8192;             // ushort [32][64][64]
  constexpr size_t O_WCAT = O_OTT + 262144;          // ushort [1024][256]
  constexpr size_t O_BCAT = O_WCAT + 524288;         // float  [1024]
  constexpr size_t O_WOUT = O_BCAT + 4096;           // ushort [256][512]
  constexpr size_t O_WSL  = O_WOUT + 262144;         // ushort [64][64]
  constexpr size_t NEED   = O_WSL + 8192;            // ~386 MiB
  if (ws_size < NEED) return;

  ushort* fxb  = (ushort*)(ws + O_FX);
  ushort* xmb  = (ushort*)(ws + O_XM);
  ushort* swn  = (ushort*)(ws + O_SWN);
  ushort* xb   = (ushort*)(ws + O_SWN);   // aliases swn: xb dead before k_slice writes swn
  float*  sraw = (float*)(ws + O_SRAW);
  float*  cs   = (float*)(ws + O_CS);
  ushort* ott  = (ushort*)(ws + O_OTT);
  ushort* Wcat = (ushort*)(ws + O_WCAT);
  float*  bcat = (float*)(ws + O_BCAT);
  ushort* Wo16 = (ushort*)(ws + O_WOUT);
  ushort* Wsl16= (ushort*)(ws + O_WSL);
  ushort* oxb  = xmb;   // out_x aliases xm (dead after k_slice)

  k_prep<<<1024,256,0,stream>>>(Wfx,bfx,Wx,bx,Wout,Wsl,Wcat,bcat,Wo16,Wsl16);
  k_zero<<<520,256,0,stream>>>(sraw, 133120);        // sraw + cs contiguous
  k_xcvt<<<16384,256,0,stream>>>(x,xb);
  k_proj<<<dim3(1024,8),256,0,stream>>>(xb,Wcat,bcat,fxb,xmb);
  k_slice<<<2048,256,0,stream>>>(xmb,Wsl16,bsl,temp,swn,cs);
  k_accum<<<dim3(32,32),256,0,stream>>>(swn,fxb,sraw);
  k_attn<<<32,256,0,stream>>>(sraw,cs,Wq,Wk,Wv,ott);
  k_deslice<<<4096,256,0,stream>>>(swn,ott,oxb);
  k_out<<<dim3(1024,2),256,0,stream>>>(oxb,Wo16,bout,out);
}